// Round 7
// baseline (352.148 us; speedup 1.0000x reference)
//
#include <hip/hip_runtime.h>
#include <hip/hip_bf16.h>

#define S 2048
#define D 1024
#define NE 8
#define HF 4096
#define HH 8192
#define BK 32
#define ACT_ROWS 4224  // 4096 + 128 pad
#define MAXRB 40       // max 128-row blocks: 4096/128 + 8 - 1 = 39

typedef __attribute__((ext_vector_type(8))) __bf16 bf16x8;
typedef __attribute__((ext_vector_type(4))) float f32x4;

__device__ __forceinline__ unsigned cvtpk(float lo, float hi) {
  unsigned r;
  asm("v_cvt_pk_bf16_f32 %0, %1, %2" : "=v"(r) : "v"(lo), "v"(hi));
  return r;  // RNE, lo in low 16
}
__device__ __forceinline__ unsigned bf16b(float f) {
  unsigned b = __float_as_uint(f);
  return (b + 0x7fffu + ((b >> 16) & 1u)) >> 16;  // RNE fp32->bf16 (finite)
}
__device__ __forceinline__ void gll16(const ushort* g, ushort* l) {
  __builtin_amdgcn_global_load_lds(
      (const __attribute__((address_space(1))) void*)g,
      (__attribute__((address_space(3))) void*)l, 16, 0, 0);
}

// ------------- W: [E][R][C] fp32 -> [E][C][R] bf16 (transpose + convert) -------------
__global__ __launch_bounds__(256) void transpose_convert(const float* __restrict__ src,
                                                         ushort* __restrict__ dst,
                                                         int R, int C) {
  const int e = blockIdx.z;
  const int n0 = blockIdx.x * 64;
  const int k0 = blockIdx.y * 64;
  const float* Sp = src + (size_t)e * R * C;
  ushort* Dp = dst + (size_t)e * R * C;
  __shared__ unsigned T[64][33];
  const int t = threadIdx.x;
  const int kp = t >> 4;         // 0..15
  const int nn = (t & 15) * 4;   // 0..60
#pragma unroll
  for (int j = 0; j < 2; ++j) {
    const int ka = k0 + 2 * kp + 32 * j;
    float4 a = *(const float4*)(Sp + (size_t)ka * C + n0 + nn);
    float4 b = *(const float4*)(Sp + (size_t)(ka + 1) * C + n0 + nn);
    T[nn + 0][kp + 16 * j] = cvtpk(a.x, b.x);
    T[nn + 1][kp + 16 * j] = cvtpk(a.y, b.y);
    T[nn + 2][kp + 16 * j] = cvtpk(a.z, b.z);
    T[nn + 3][kp + 16 * j] = cvtpk(a.w, b.w);
  }
  __syncthreads();
  const int n = t >> 2;
  const int kq = (t & 3) * 8;
  uint4 v0 = *(const uint4*)&T[n][kq];
  uint4 v1 = *(const uint4*)&T[n][kq + 4];
  uint4* out = (uint4*)(Dp + (size_t)(n0 + n) * R + k0 + kq * 2);
  out[0] = v0;
  out[1] = v1;
}

// ------- gating + x->bf16 fused: one block (256 thr) per token -------
__global__ __launch_bounds__(256) void gate_kernel(
    const float* __restrict__ x, const float* __restrict__ gw,
    const float* __restrict__ gb, ushort* __restrict__ xb,
    int* __restrict__ mi0, int* __restrict__ mi1,
    float* __restrict__ mw0, float* __restrict__ mw1) {
  const int t = blockIdx.x;
  const int l = threadIdx.x;  // 0..255, handles d = 4l..4l+3
  const float4 xv = ((const float4*)(x + (size_t)t * D))[l];
  uint2 wv = {cvtpk(xv.x, xv.y), cvtpk(xv.z, xv.w)};
  ((uint2*)(xb + (size_t)t * D))[l] = wv;

  float xa[4] = {xv.x, xv.y, xv.z, xv.w};
  float acc[NE];
#pragma unroll
  for (int e = 0; e < NE; ++e) acc[e] = 0.f;
  const float* g0 = gw + (size_t)(4 * l) * NE;
#pragma unroll
  for (int j = 0; j < 4; ++j)
#pragma unroll
    for (int e = 0; e < NE; ++e) acc[e] += xa[j] * g0[j * NE + e];
#pragma unroll
  for (int e = 0; e < NE; ++e) {
    float v = acc[e];
#pragma unroll
    for (int off = 32; off > 0; off >>= 1) v += __shfl_xor(v, off);
    acc[e] = v;
  }
  __shared__ float sm[4][NE];
  const int wid = l >> 6;
  if ((l & 63) == 0) {
#pragma unroll
    for (int e = 0; e < NE; ++e) sm[wid][e] = acc[e];
  }
  __syncthreads();
  if (l == 0) {
    float lg[NE];
#pragma unroll
    for (int e = 0; e < NE; ++e)
      lg[e] = sm[0][e] + sm[1][e] + sm[2][e] + sm[3][e] + gb[e];
    int i0 = 0; float m0 = lg[0];
#pragma unroll
    for (int e = 1; e < NE; ++e) if (lg[e] > m0) { m0 = lg[e]; i0 = e; }  // strict >: jax tie-break
    int i1 = -1; float m1 = -3.4e38f;
#pragma unroll
    for (int e = 0; e < NE; ++e) if (e != i0 && lg[e] > m1) { m1 = lg[e]; i1 = e; }
    float p = __expf(m1 - m0);
    float inv = 1.f / (1.f + p);
    mi0[t] = i0; mi1[t] = i1;
    mw0[t] = inv; mw1[t] = p * inv;
  }
}

// --- routing: counts + prefix + slots(+weights) + compact rowblock table ---
__global__ __launch_bounds__(1024) void route_kernel(
    const int* __restrict__ mi0, const int* __restrict__ mi1,
    const float* __restrict__ mw0, const float* __restrict__ mw1,
    int* __restrict__ counts, int* __restrict__ basep, int* __restrict__ list_tok,
    float* __restrict__ list_w,
    int* __restrict__ rb_e, int* __restrict__ rb_row0, int* __restrict__ rb_n) {
  __shared__ int cnt[NE];
  __shared__ int cur[NE];
  const int t = threadIdx.x;
  if (t < NE) cnt[t] = 0;
  __syncthreads();
  const int e0a = mi0[t], e1a = mi1[t];
  const int e0b = mi0[t + 1024], e1b = mi1[t + 1024];
  atomicAdd(&cnt[e0a], 1); atomicAdd(&cnt[e1a], 1);
  atomicAdd(&cnt[e0b], 1); atomicAdd(&cnt[e1b], 1);
  __syncthreads();
  if (t == 0) {
    int s = 0;
#pragma unroll
    for (int e = 0; e < NE; ++e) { basep[e] = s; cur[e] = s; s += cnt[e]; }
    basep[NE] = s;
    int nrb = 0;
    for (int e = 0; e < NE; ++e)
      for (int r0 = 0; r0 < cnt[e]; r0 += 128) {
        rb_e[nrb] = e; rb_row0[nrb] = r0; ++nrb;
      }
    *rb_n = nrb;  // <= 39
  }
  if (t < NE) counts[t] = cnt[t];
  __syncthreads();
  int r;
  r = atomicAdd(&cur[e0a], 1); list_tok[r] = t;        list_w[r] = mw0[t];
  r = atomicAdd(&cur[e1a], 1); list_tok[r] = t;        list_w[r] = mw1[t];
  r = atomicAdd(&cur[e0b], 1); list_tok[r] = t + 1024; list_w[r] = mw0[t + 1024];
  r = atomicAdd(&cur[e1b], 1); list_tok[r] = t + 1024; list_w[r] = mw1[t + 1024];
}

// ------- out init: out[t] = w0*b2[e0] + w1*b2[e1] (gemm2 atomically adds the rest) -------
__global__ __launch_bounds__(256) void init_out(
    const float* __restrict__ b2, const int* __restrict__ mi0, const int* __restrict__ mi1,
    const float* __restrict__ mw0, const float* __restrict__ mw1, float* __restrict__ out) {
  const int t = blockIdx.x;
  const int l = threadIdx.x;  // 256 * float4 = 1024
  const float w0 = mw0[t], w1 = mw1[t];
  float4 a = ((const float4*)(b2 + (size_t)mi0[t] * D))[l];
  float4 b = ((const float4*)(b2 + (size_t)mi1[t] * D))[l];
  float4 r = {w0 * a.x + w1 * b.x, w0 * a.y + w1 * b.y,
              w0 * a.z + w1 * b.z, w0 * a.w + w1 * b.w};
  ((float4*)(out + (size_t)t * D))[l] = r;
}

// -------- GEMM1 + SwiGLU: 128 rows x 64 act-cols (both H halves), bf16 all-MFMA --------
// grid: x = jt (fastest, 64), y = compact rowblock id (<=40, ~all active)
__global__ __launch_bounds__(256) void gemm1_kernel(
    const ushort* __restrict__ xb, const ushort* __restrict__ w1t,
    const float* __restrict__ b1, const int* __restrict__ counts,
    const int* __restrict__ basep, const int* __restrict__ list_tok,
    const int* __restrict__ rb_e, const int* __restrict__ rb_row0,
    const int* __restrict__ rb_n, ushort* __restrict__ act_buf) {
  const int rb = blockIdx.y;
  if (rb >= *rb_n) return;
  const int e = rb_e[rb];
  const int row0 = rb_row0[rb];
  const int cnt = counts[e];
  const int jt = blockIdx.x * 64;
  const ushort* __restrict__ W = w1t + (size_t)e * D * HH;  // [n=8192][k=1024] bf16
  const int gbase = basep[e];

  __shared__ ushort As[2][128][BK];
  __shared__ ushort Bs[2][128][BK];  // rows 0..63: x-half col jt+n ; 64..127: gate-half

  const int tid = threadIdx.x;
  const int w = tid >> 6;
  const int i = tid & 63;

  const int rA0 = w * 32 + (i >> 2);
  const int rA1 = rA0 + 16;
  int s0 = row0 + rA0; if (s0 >= cnt) s0 = cnt - 1;
  int s1 = row0 + rA1; if (s1 >= cnt) s1 = cnt - 1;
  const ushort* pa0 = xb + (size_t)list_tok[gbase + s0] * D + (i & 3) * 8;
  const ushort* pa1 = xb + (size_t)list_tok[gbase + s1] * D + (i & 3) * 8;
  const ushort* pb0 = W + ((size_t)(rA0 >> 6) * HF + jt + (rA0 & 63)) * D + (i & 3) * 8;
  const ushort* pb1 = W + ((size_t)(rA1 >> 6) * HF + jt + (rA1 & 63)) * D + (i & 3) * 8;

  const int wm = (w >> 1) * 64;
  const int wn = (w & 1) * 32;
  const int lr = i & 15;
  const int kg = i >> 4;

  f32x4 acc[2][4][2] = {};  // [half][mi][ni]

  gll16(pa0, &As[0][w * 32][0]);
  gll16(pa1, &As[0][w * 32 + 16][0]);
  gll16(pb0, &Bs[0][w * 32][0]);
  gll16(pb1, &Bs[0][w * 32 + 16][0]);
  __syncthreads();

  int cur = 0;
#pragma unroll 1
  for (int it = 0; it < D / BK; ++it) {
    if (it + 1 < D / BK) {
      const int ko = (it + 1) * BK;
      gll16(pa0 + ko, &As[cur ^ 1][w * 32][0]);
      gll16(pa1 + ko, &As[cur ^ 1][w * 32 + 16][0]);
      gll16(pb0 + ko, &Bs[cur ^ 1][w * 32][0]);
      gll16(pb1 + ko, &Bs[cur ^ 1][w * 32 + 16][0]);
    }
    bf16x8 af[4], bfr[2][2];
#pragma unroll
    for (int mi = 0; mi < 4; ++mi)
      af[mi] = *(const bf16x8*)&As[cur][wm + mi * 16 + lr][kg * 8];
#pragma unroll
    for (int h = 0; h < 2; ++h)
#pragma unroll
      for (int ni = 0; ni < 2; ++ni)
        bfr[h][ni] = *(const bf16x8*)&Bs[cur][h * 64 + wn + ni * 16 + lr][kg * 8];
#pragma unroll
    for (int h = 0; h < 2; ++h)
#pragma unroll
      for (int mi = 0; mi < 4; ++mi)
#pragma unroll
        for (int ni = 0; ni < 2; ++ni)
          acc[h][mi][ni] = __builtin_amdgcn_mfma_f32_16x16x32_bf16(af[mi], bfr[h][ni],
                                                                   acc[h][mi][ni], 0, 0, 0);
    __syncthreads();
    cur ^= 1;
  }

#pragma unroll
  for (int mi = 0; mi < 4; ++mi)
#pragma unroll
    for (int ni = 0; ni < 2; ++ni) {
      const int c = jt + wn + ni * 16 + lr;
      const float bx = b1[(size_t)e * HH + c];
      const float bg = b1[(size_t)e * HH + HF + c];
      f32x4 vx = acc[0][mi][ni];
      f32x4 vg = acc[1][mi][ni];
#pragma unroll
      for (int q = 0; q < 4; ++q) {
        const int slot = row0 + wm + mi * 16 + kg * 4 + q;
        if (slot < cnt) {
          float xv = vx[q] + bx;
          float g = vg[q] + bg;
          float a = g / (1.f + __expf(-g)) * xv;
          act_buf[(size_t)(gbase + slot) * HF + c] = (ushort)bf16b(a);
        }
      }
    }
}

// ---------- GEMM2 (K-split 4): weighted atomic accumulate into out ----------
// grid: x = jt (fastest, 8), y = compact rowblock id, z = split
__global__ __launch_bounds__(256) void gemm2_kernel(
    const ushort* __restrict__ act_buf, const ushort* __restrict__ w2t,
    const int* __restrict__ counts, const int* __restrict__ basep,
    const int* __restrict__ list_tok, const float* __restrict__ list_w,
    const int* __restrict__ rb_e, const int* __restrict__ rb_row0,
    const int* __restrict__ rb_n, float* __restrict__ out) {
  const int rb = blockIdx.y;
  if (rb >= *rb_n) return;
  const int e = rb_e[rb];
  const int row0 = rb_row0[rb];
  const int cnt = counts[e];
  const int split = blockIdx.z;
  const int jt = blockIdx.x * 128;
  const ushort* __restrict__ W = w2t + (size_t)e * HF * D;  // [n=1024][kf=4096] bf16
  const int gbase = basep[e];

  __shared__ ushort As[2][128][BK];
  __shared__ ushort Bs[2][128][BK];

  const int tid = threadIdx.x;
  const int w = tid >> 6;
  const int i = tid & 63;

  const int r0 = w * 32 + (i >> 2);
  const size_t kbase = (size_t)split * (HF / 4);
  const ushort* pa0 = act_buf + (size_t)(gbase + row0 + r0) * HF + kbase + (i & 3) * 8;
  const ushort* pa1 = pa0 + (size_t)16 * HF;
  const ushort* pb0 = W + (size_t)(jt + r0) * HF + kbase + (i & 3) * 8;
  const ushort* pb1 = pb0 + (size_t)16 * HF;

  const int wm = (w >> 1) * 64;
  const int wn = (w & 1) * 64;
  const int lr = i & 15;
  const int kg = i >> 4;

  f32x4 acc[4][4] = {};

  gll16(pa0, &As[0][w * 32][0]);
  gll16(pa1, &As[0][w * 32 + 16][0]);
  gll16(pb0, &Bs[0][w * 32][0]);
  gll16(pb1, &Bs[0][w * 32 + 16][0]);
  __syncthreads();

  int cur = 0;
#pragma unroll 1
  for (int it = 0; it < (HF / 4) / BK; ++it) {
    if (it + 1 < (HF / 4) / BK) {
      const int ko = (it + 1) * BK;
      gll16(pa0 + ko, &As[cur ^ 1][w * 32][0]);
      gll16(pa1 + ko, &As[cur ^ 1][w * 32 + 16][0]);
      gll16(pb0 + ko, &Bs[cur ^ 1][w * 32][0]);
      gll16(pb1 + ko, &Bs[cur ^ 1][w * 32 + 16][0]);
    }
    bf16x8 af[4], bfr[4];
#pragma unroll
    for (int mi = 0; mi < 4; ++mi)
      af[mi] = *(const bf16x8*)&As[cur][wm + mi * 16 + lr][kg * 8];
#pragma unroll
    for (int ni = 0; ni < 4; ++ni)
      bfr[ni] = *(const bf16x8*)&Bs[cur][wn + ni * 16 + lr][kg * 8];
#pragma unroll
    for (int mi = 0; mi < 4; ++mi)
#pragma unroll
      for (int ni = 0; ni < 4; ++ni)
        acc[mi][ni] = __builtin_amdgcn_mfma_f32_16x16x32_bf16(af[mi], bfr[ni],
                                                              acc[mi][ni], 0, 0, 0);
    __syncthreads();
    cur ^= 1;
  }

#pragma unroll
  for (int mi = 0; mi < 4; ++mi) {
    const int slotb = row0 + wm + mi * 16 + kg * 4;
#pragma unroll
    for (int q = 0; q < 4; ++q) {
      const int slot = slotb + q;
      if (slot < cnt) {
        const int tok = list_tok[gbase + slot];
        const float wgt = list_w[gbase + slot];
        float* orow = out + (size_t)tok * D + jt + wn + lr;
#pragma unroll
        for (int ni = 0; ni < 4; ++ni)
          atomicAdd(orow + ni * 16, wgt * acc[mi][ni][q]);
      }
    }
  }
}

extern "C" void kernel_launch(void* const* d_in, const int* in_sizes, int n_in,
                              void* d_out, int out_size, void* d_ws, size_t ws_size,
                              hipStream_t stream) {
  const float* x  = (const float*)d_in[0];
  const float* gw = (const float*)d_in[1];
  const float* gb = (const float*)d_in[2];
  const float* w1 = (const float*)d_in[3];
  const float* b1 = (const float*)d_in[4];
  const float* w2 = (const float*)d_in[5];
  const float* b2 = (const float*)d_in[6];
  float* out = (float*)d_out;

  char* ws = (char*)d_ws;
  int*   counts   = (int*)(ws + 0);
  int*   basep    = (int*)(ws + 64);
  int*   rb_n     = (int*)(ws + 128);
  int*   rb_e     = (int*)(ws + 192);                       // 40 ints
  int*   rb_row0  = (int*)(ws + 384);                       // 40 ints
  int*   mi0      = (int*)(ws + 1024);                      // 8 KB each
  int*   mi1      = (int*)(ws + 9216);
  float* mw0      = (float*)(ws + 17408);
  float* mw1      = (float*)(ws + 25600);
  int*   list_tok = (int*)(ws + 33792);                     // 16 KB
  float* list_w   = (float*)(ws + 50176);                   // 16 KB
  ushort* xb      = (ushort*)(ws + 66560);                  // 4 MB
  ushort* act_buf = (ushort*)(ws + 4260864);                // 34.6 MB (4224 x 4096 bf16)
  ushort* w1t     = (ushort*)(ws + 38863872);               // 134 MB
  ushort* w2t     = (ushort*)(ws + 173081600);              // 67 MB (end: 240 MB)

  transpose_convert<<<dim3(HH / 64, D / 64, NE), 256, 0, stream>>>(w1, w1t, D, HH);
  transpose_convert<<<dim3(D / 64, HF / 64, NE), 256, 0, stream>>>(w2, w2t, HF, D);
  gate_kernel<<<S, 256, 0, stream>>>(x, gw, gb, xb, mi0, mi1, mw0, mw1);
  route_kernel<<<1, 1024, 0, stream>>>(mi0, mi1, mw0, mw1, counts, basep, list_tok,
                                       list_w, rb_e, rb_row0, rb_n);
  init_out<<<S, 256, 0, stream>>>(b2, mi0, mi1, mw0, mw1, out);
  gemm1_kernel<<<dim3(64, MAXRB), 256, 0, stream>>>(xb, w1t, b1, counts, basep, list_tok,
                                                    rb_e, rb_row0, rb_n, act_buf);
  gemm2_kernel<<<dim3(8, MAXRB, 4), 256, 0, stream>>>(act_buf, w2t, counts, basep,
                                                      list_tok, list_w,
                                                      rb_e, rb_row0, rb_n, out);
}

// Round 8
// 320.857 us; speedup vs baseline: 1.0975x; 1.0975x over previous
//
#include <hip/hip_runtime.h>
#include <hip/hip_bf16.h>

#define S 2048
#define D 1024
#define NE 8
#define HF 4096
#define HH 8192
#define BK 32
#define ACT_ROWS 4224  // 4096 + 128 pad
#define MAXRB 40       // max 128-row blocks: 4096/128 + 8 - 1 = 39

typedef __attribute__((ext_vector_type(8))) __bf16 bf16x8;
typedef __attribute__((ext_vector_type(4))) float f32x4;

__device__ __forceinline__ unsigned cvtpk(float lo, float hi) {
  unsigned r;
  asm("v_cvt_pk_bf16_f32 %0, %1, %2" : "=v"(r) : "v"(lo), "v"(hi));
  return r;  // RNE, lo in low 16
}
__device__ __forceinline__ unsigned bf16b(float f) {
  unsigned b = __float_as_uint(f);
  return (b + 0x7fffu + ((b >> 16) & 1u)) >> 16;  // RNE fp32->bf16 (finite)
}
__device__ __forceinline__ void gll16(const ushort* g, ushort* l) {
  __builtin_amdgcn_global_load_lds(
      (const __attribute__((address_space(1))) void*)g,
      (__attribute__((address_space(3))) void*)l, 16, 0, 0);
}

// ------------- W: [E][R][C] fp32 -> [E][C][R] bf16 (transpose + convert) -------------
__global__ __launch_bounds__(256) void transpose_convert(const float* __restrict__ src,
                                                         ushort* __restrict__ dst,
                                                         int R, int C) {
  const int e = blockIdx.z;
  const int n0 = blockIdx.x * 64;
  const int k0 = blockIdx.y * 64;
  const float* Sp = src + (size_t)e * R * C;
  ushort* Dp = dst + (size_t)e * R * C;
  __shared__ unsigned T[64][33];
  const int t = threadIdx.x;
  const int kp = t >> 4;         // 0..15
  const int nn = (t & 15) * 4;   // 0..60
#pragma unroll
  for (int j = 0; j < 2; ++j) {
    const int ka = k0 + 2 * kp + 32 * j;
    float4 a = *(const float4*)(Sp + (size_t)ka * C + n0 + nn);
    float4 b = *(const float4*)(Sp + (size_t)(ka + 1) * C + n0 + nn);
    T[nn + 0][kp + 16 * j] = cvtpk(a.x, b.x);
    T[nn + 1][kp + 16 * j] = cvtpk(a.y, b.y);
    T[nn + 2][kp + 16 * j] = cvtpk(a.z, b.z);
    T[nn + 3][kp + 16 * j] = cvtpk(a.w, b.w);
  }
  __syncthreads();
  const int n = t >> 2;
  const int kq = (t & 3) * 8;
  uint4 v0 = *(const uint4*)&T[n][kq];
  uint4 v1 = *(const uint4*)&T[n][kq + 4];
  uint4* out = (uint4*)(Dp + (size_t)(n0 + n) * R + k0 + kq * 2);
  out[0] = v0;
  out[1] = v1;
}

// ------- gating + x->bf16 fused: one block (256 thr) per token -------
__global__ __launch_bounds__(256) void gate_kernel(
    const float* __restrict__ x, const float* __restrict__ gw,
    const float* __restrict__ gb, ushort* __restrict__ xb,
    int* __restrict__ mi0, int* __restrict__ mi1,
    float* __restrict__ mw0, float* __restrict__ mw1) {
  const int t = blockIdx.x;
  const int l = threadIdx.x;  // 0..255, handles d = 4l..4l+3
  const float4 xv = ((const float4*)(x + (size_t)t * D))[l];
  uint2 wv = {cvtpk(xv.x, xv.y), cvtpk(xv.z, xv.w)};
  ((uint2*)(xb + (size_t)t * D))[l] = wv;

  float xa[4] = {xv.x, xv.y, xv.z, xv.w};
  float acc[NE];
#pragma unroll
  for (int e = 0; e < NE; ++e) acc[e] = 0.f;
  const float* g0 = gw + (size_t)(4 * l) * NE;
#pragma unroll
  for (int j = 0; j < 4; ++j)
#pragma unroll
    for (int e = 0; e < NE; ++e) acc[e] += xa[j] * g0[j * NE + e];
#pragma unroll
  for (int e = 0; e < NE; ++e) {
    float v = acc[e];
#pragma unroll
    for (int off = 32; off > 0; off >>= 1) v += __shfl_xor(v, off);
    acc[e] = v;
  }
  __shared__ float sm[4][NE];
  const int wid = l >> 6;
  if ((l & 63) == 0) {
#pragma unroll
    for (int e = 0; e < NE; ++e) sm[wid][e] = acc[e];
  }
  __syncthreads();
  if (l == 0) {
    float lg[NE];
#pragma unroll
    for (int e = 0; e < NE; ++e)
      lg[e] = sm[0][e] + sm[1][e] + sm[2][e] + sm[3][e] + gb[e];
    int i0 = 0; float m0 = lg[0];
#pragma unroll
    for (int e = 1; e < NE; ++e) if (lg[e] > m0) { m0 = lg[e]; i0 = e; }  // strict >: jax tie-break
    int i1 = -1; float m1 = -3.4e38f;
#pragma unroll
    for (int e = 0; e < NE; ++e) if (e != i0 && lg[e] > m1) { m1 = lg[e]; i1 = e; }
    float p = __expf(m1 - m0);
    float inv = 1.f / (1.f + p);
    mi0[t] = i0; mi1[t] = i1;
    mw0[t] = inv; mw1[t] = p * inv;
  }
}

// --- routing: counts + prefix + slots + compact rowblock table (one block) ---
__global__ __launch_bounds__(1024) void route_kernel(
    const int* __restrict__ mi0, const int* __restrict__ mi1,
    int* __restrict__ counts, int* __restrict__ basep, int* __restrict__ list_tok,
    int* __restrict__ mr0, int* __restrict__ mr1,
    int* __restrict__ rb_e, int* __restrict__ rb_row0, int* __restrict__ rb_n) {
  __shared__ int cnt[NE];
  __shared__ int cur[NE];
  const int t = threadIdx.x;
  if (t < NE) cnt[t] = 0;
  __syncthreads();
  const int e0a = mi0[t], e1a = mi1[t];
  const int e0b = mi0[t + 1024], e1b = mi1[t + 1024];
  atomicAdd(&cnt[e0a], 1); atomicAdd(&cnt[e1a], 1);
  atomicAdd(&cnt[e0b], 1); atomicAdd(&cnt[e1b], 1);
  __syncthreads();
  if (t == 0) {
    int s = 0;
#pragma unroll
    for (int e = 0; e < NE; ++e) { basep[e] = s; cur[e] = s; s += cnt[e]; }
    basep[NE] = s;
    int nrb = 0;
    for (int e = 0; e < NE; ++e)
      for (int r0 = 0; r0 < cnt[e]; r0 += 128) {
        rb_e[nrb] = e; rb_row0[nrb] = r0; ++nrb;
      }
    *rb_n = nrb;  // <= 39
  }
  if (t < NE) counts[t] = cnt[t];
  __syncthreads();
  int r;
  r = atomicAdd(&cur[e0a], 1); list_tok[r] = t; mr0[t] = r;
  r = atomicAdd(&cur[e1a], 1); list_tok[r] = t; mr1[t] = r;
  r = atomicAdd(&cur[e0b], 1); list_tok[r] = t + 1024; mr0[t + 1024] = r;
  r = atomicAdd(&cur[e1b], 1); list_tok[r] = t + 1024; mr1[t + 1024] = r;
}

// -------- GEMM1 + SwiGLU: 128 rows x 64 act-cols (both H halves), bf16 all-MFMA --------
// grid: x = jt (fastest, 64), y = compact rowblock id (<=40, ~all active)
__global__ __launch_bounds__(256) void gemm1_kernel(
    const ushort* __restrict__ xb, const ushort* __restrict__ w1t,
    const float* __restrict__ b1, const int* __restrict__ counts,
    const int* __restrict__ basep, const int* __restrict__ list_tok,
    const int* __restrict__ rb_e, const int* __restrict__ rb_row0,
    const int* __restrict__ rb_n, ushort* __restrict__ act_buf) {
  const int rb = blockIdx.y;
  if (rb >= *rb_n) return;
  const int e = rb_e[rb];
  const int row0 = rb_row0[rb];
  const int cnt = counts[e];
  const int jt = blockIdx.x * 64;
  const ushort* __restrict__ W = w1t + (size_t)e * D * HH;  // [n=8192][k=1024] bf16
  const int gbase = basep[e];

  __shared__ ushort As[2][128][BK];
  __shared__ ushort Bs[2][128][BK];  // rows 0..63: x-half col jt+n ; 64..127: gate-half

  const int tid = threadIdx.x;
  const int w = tid >> 6;
  const int i = tid & 63;

  const int rA0 = w * 32 + (i >> 2);
  const int rA1 = rA0 + 16;
  int s0 = row0 + rA0; if (s0 >= cnt) s0 = cnt - 1;
  int s1 = row0 + rA1; if (s1 >= cnt) s1 = cnt - 1;
  const ushort* pa0 = xb + (size_t)list_tok[gbase + s0] * D + (i & 3) * 8;
  const ushort* pa1 = xb + (size_t)list_tok[gbase + s1] * D + (i & 3) * 8;
  const ushort* pb0 = W + ((size_t)(rA0 >> 6) * HF + jt + (rA0 & 63)) * D + (i & 3) * 8;
  const ushort* pb1 = W + ((size_t)(rA1 >> 6) * HF + jt + (rA1 & 63)) * D + (i & 3) * 8;

  const int wm = (w >> 1) * 64;
  const int wn = (w & 1) * 32;
  const int lr = i & 15;
  const int kg = i >> 4;

  f32x4 acc[2][4][2] = {};  // [half][mi][ni]

  gll16(pa0, &As[0][w * 32][0]);
  gll16(pa1, &As[0][w * 32 + 16][0]);
  gll16(pb0, &Bs[0][w * 32][0]);
  gll16(pb1, &Bs[0][w * 32 + 16][0]);
  __syncthreads();

  int cur = 0;
#pragma unroll 1
  for (int it = 0; it < D / BK; ++it) {
    if (it + 1 < D / BK) {
      const int ko = (it + 1) * BK;
      gll16(pa0 + ko, &As[cur ^ 1][w * 32][0]);
      gll16(pa1 + ko, &As[cur ^ 1][w * 32 + 16][0]);
      gll16(pb0 + ko, &Bs[cur ^ 1][w * 32][0]);
      gll16(pb1 + ko, &Bs[cur ^ 1][w * 32 + 16][0]);
    }
    bf16x8 af[4], bfr[2][2];
#pragma unroll
    for (int mi = 0; mi < 4; ++mi)
      af[mi] = *(const bf16x8*)&As[cur][wm + mi * 16 + lr][kg * 8];
#pragma unroll
    for (int h = 0; h < 2; ++h)
#pragma unroll
      for (int ni = 0; ni < 2; ++ni)
        bfr[h][ni] = *(const bf16x8*)&Bs[cur][h * 64 + wn + ni * 16 + lr][kg * 8];
#pragma unroll
    for (int h = 0; h < 2; ++h)
#pragma unroll
      for (int mi = 0; mi < 4; ++mi)
#pragma unroll
        for (int ni = 0; ni < 2; ++ni)
          acc[h][mi][ni] = __builtin_amdgcn_mfma_f32_16x16x32_bf16(af[mi], bfr[h][ni],
                                                                   acc[h][mi][ni], 0, 0, 0);
    __syncthreads();
    cur ^= 1;
  }

#pragma unroll
  for (int mi = 0; mi < 4; ++mi)
#pragma unroll
    for (int ni = 0; ni < 2; ++ni) {
      const int c = jt + wn + ni * 16 + lr;
      const float bx = b1[(size_t)e * HH + c];
      const float bg = b1[(size_t)e * HH + HF + c];
      f32x4 vx = acc[0][mi][ni];
      f32x4 vg = acc[1][mi][ni];
#pragma unroll
      for (int q = 0; q < 4; ++q) {
        const int slot = row0 + wm + mi * 16 + kg * 4 + q;
        if (slot < cnt) {
          float xv = vx[q] + bx;
          float g = vg[q] + bg;
          float a = g / (1.f + __expf(-g)) * xv;
          act_buf[(size_t)(gbase + slot) * HF + c] = (ushort)bf16b(a);
        }
      }
    }
}

// -------------------- GEMM2 (K-split 2): oe[split] = act @ W2[e] --------------------
// grid: x = jt (fastest, 8), y = compact rowblock id, z = split
__global__ __launch_bounds__(256) void gemm2_kernel(
    const ushort* __restrict__ act_buf, const ushort* __restrict__ w2t,
    const int* __restrict__ counts, const int* __restrict__ basep,
    const int* __restrict__ rb_e, const int* __restrict__ rb_row0,
    const int* __restrict__ rb_n, float* __restrict__ oe) {
  const int rb = blockIdx.y;
  if (rb >= *rb_n) return;
  const int e = rb_e[rb];
  const int row0 = rb_row0[rb];
  const int cnt = counts[e];
  const int split = blockIdx.z;
  const int jt = blockIdx.x * 128;
  const ushort* __restrict__ W = w2t + (size_t)e * HF * D;  // [n=1024][kf=4096] bf16
  const int gbase = basep[e];

  __shared__ ushort As[2][128][BK];
  __shared__ ushort Bs[2][128][BK];

  const int tid = threadIdx.x;
  const int w = tid >> 6;
  const int i = tid & 63;

  const int r0 = w * 32 + (i >> 2);
  const size_t kbase = (size_t)split * (HF / 2);
  const ushort* pa0 = act_buf + (size_t)(gbase + row0 + r0) * HF + kbase + (i & 3) * 8;
  const ushort* pa1 = pa0 + (size_t)16 * HF;
  const ushort* pb0 = W + (size_t)(jt + r0) * HF + kbase + (i & 3) * 8;
  const ushort* pb1 = pb0 + (size_t)16 * HF;

  const int wm = (w >> 1) * 64;
  const int wn = (w & 1) * 64;
  const int lr = i & 15;
  const int kg = i >> 4;

  f32x4 acc[4][4] = {};

  gll16(pa0, &As[0][w * 32][0]);
  gll16(pa1, &As[0][w * 32 + 16][0]);
  gll16(pb0, &Bs[0][w * 32][0]);
  gll16(pb1, &Bs[0][w * 32 + 16][0]);
  __syncthreads();

  int cur = 0;
#pragma unroll 1
  for (int it = 0; it < (HF / 2) / BK; ++it) {
    if (it + 1 < (HF / 2) / BK) {
      const int ko = (it + 1) * BK;
      gll16(pa0 + ko, &As[cur ^ 1][w * 32][0]);
      gll16(pa1 + ko, &As[cur ^ 1][w * 32 + 16][0]);
      gll16(pb0 + ko, &Bs[cur ^ 1][w * 32][0]);
      gll16(pb1 + ko, &Bs[cur ^ 1][w * 32 + 16][0]);
    }
    bf16x8 af[4], bfr[4];
#pragma unroll
    for (int mi = 0; mi < 4; ++mi)
      af[mi] = *(const bf16x8*)&As[cur][wm + mi * 16 + lr][kg * 8];
#pragma unroll
    for (int ni = 0; ni < 4; ++ni)
      bfr[ni] = *(const bf16x8*)&Bs[cur][wn + ni * 16 + lr][kg * 8];
#pragma unroll
    for (int mi = 0; mi < 4; ++mi)
#pragma unroll
      for (int ni = 0; ni < 4; ++ni)
        acc[mi][ni] = __builtin_amdgcn_mfma_f32_16x16x32_bf16(af[mi], bfr[ni],
                                                              acc[mi][ni], 0, 0, 0);
    __syncthreads();
    cur ^= 1;
  }

#pragma unroll
  for (int mi = 0; mi < 4; ++mi)
#pragma unroll
    for (int ni = 0; ni < 4; ++ni) {
      f32x4 v = acc[mi][ni];
#pragma unroll
      for (int q = 0; q < 4; ++q) {
        const int slot = row0 + wm + mi * 16 + kg * 4 + q;
        if (slot < cnt)
          oe[((size_t)split * ACT_ROWS + gbase + slot) * D + jt + wn + ni * 16 + lr] = v[q];
      }
    }
}

// ---------------- combine: out[t] = w0*(oe0[r0]+oe1[r0]+b2[e0]) + w1*(...) ----------------
__global__ void combine_kernel(const float* __restrict__ oe,
                               const int* __restrict__ mr0, const int* __restrict__ mr1,
                               const float* __restrict__ mw0, const float* __restrict__ mw1,
                               const int* __restrict__ mi0, const int* __restrict__ mi1,
                               const float* __restrict__ b2, float* __restrict__ out) {
  const int t = blockIdx.x;
  const int l = threadIdx.x;
  const float w0 = mw0[t], w1 = mw1[t];
  const float4* p00 = (const float4*)(oe + (size_t)mr0[t] * D);
  const float4* p01 = (const float4*)(oe + ((size_t)ACT_ROWS + mr0[t]) * D);
  const float4* p10 = (const float4*)(oe + (size_t)mr1[t] * D);
  const float4* p11 = (const float4*)(oe + ((size_t)ACT_ROWS + mr1[t]) * D);
  const float4* c0 = (const float4*)(b2 + (size_t)mi0[t] * D);
  const float4* c1 = (const float4*)(b2 + (size_t)mi1[t] * D);
  float4 A0 = p00[l], A1 = p01[l], B0 = p10[l], B1 = p11[l], C = c0[l], E2 = c1[l];
  float4 r;
  r.x = w0 * (A0.x + A1.x + C.x) + w1 * (B0.x + B1.x + E2.x);
  r.y = w0 * (A0.y + A1.y + C.y) + w1 * (B0.y + B1.y + E2.y);
  r.z = w0 * (A0.z + A1.z + C.z) + w1 * (B0.z + B1.z + E2.z);
  r.w = w0 * (A0.w + A1.w + C.w) + w1 * (B0.w + B1.w + E2.w);
  ((float4*)(out + (size_t)t * D))[l] = r;
}

extern "C" void kernel_launch(void* const* d_in, const int* in_sizes, int n_in,
                              void* d_out, int out_size, void* d_ws, size_t ws_size,
                              hipStream_t stream) {
  const float* x  = (const float*)d_in[0];
  const float* gw = (const float*)d_in[1];
  const float* gb = (const float*)d_in[2];
  const float* w1 = (const float*)d_in[3];
  const float* b1 = (const float*)d_in[4];
  const float* w2 = (const float*)d_in[5];
  const float* b2 = (const float*)d_in[6];
  float* out = (float*)d_out;

  char* ws = (char*)d_ws;
  int*   counts   = (int*)(ws + 0);
  int*   basep    = (int*)(ws + 64);
  int*   rb_n     = (int*)(ws + 128);
  int*   rb_e     = (int*)(ws + 192);                       // 40 ints
  int*   rb_row0  = (int*)(ws + 384);                       // 40 ints
  int*   mi0      = (int*)(ws + 1024);
  int*   mi1      = (int*)(ws + 1024 + 1 * 8192);
  int*   mr0      = (int*)(ws + 1024 + 2 * 8192);
  int*   mr1      = (int*)(ws + 1024 + 3 * 8192);
  float* mw0      = (float*)(ws + 1024 + 4 * 8192);
  float* mw1      = (float*)(ws + 1024 + 5 * 8192);
  int*   list_tok = (int*)(ws + 1024 + 6 * 8192);           // 16384 B -> ends 66560
  ushort* xb      = (ushort*)(ws + 66560);                  // 4 MB
  ushort* act_buf = (ushort*)(ws + 4260864);                // 34.6 MB (4224 x 4096 bf16)
  float*  oe      = (float*)(ws + 38863872);                // 34.6 MB (2 x 4224 x 1024 f32)
  ushort* w1t     = (ushort*)(ws + 73466880);               // 134 MB
  ushort* w2t     = (ushort*)(ws + 207684608);              // 67 MB (end: 274.8 MB)

  transpose_convert<<<dim3(HH / 64, D / 64, NE), 256, 0, stream>>>(w1, w1t, D, HH);
  transpose_convert<<<dim3(D / 64, HF / 64, NE), 256, 0, stream>>>(w2, w2t, HF, D);
  gate_kernel<<<S, 256, 0, stream>>>(x, gw, gb, xb, mi0, mi1, mw0, mw1);
  route_kernel<<<1, 1024, 0, stream>>>(mi0, mi1, counts, basep, list_tok, mr0, mr1,
                                       rb_e, rb_row0, rb_n);
  gemm1_kernel<<<dim3(64, MAXRB), 256, 0, stream>>>(xb, w1t, b1, counts, basep, list_tok,
                                                    rb_e, rb_row0, rb_n, act_buf);
  gemm2_kernel<<<dim3(8, MAXRB, 2), 256, 0, stream>>>(act_buf, w2t, counts, basep,
                                                      rb_e, rb_row0, rb_n, oe);
  combine_kernel<<<S, 256, 0, stream>>>(oe, mr0, mr1, mw0, mw1, mi0, mi1, b2, out);
}